// Round 7
// baseline (177.696 us; speedup 1.0000x reference)
//
#include <hip/hip_runtime.h>
#include <cstdint>

#define BATCH 4096
#define DIN   2560
#define FDIM  2048
#define KP    2624   // packed W cols: 2560 feats + 64 bias block (all 64-mult)
#define CAP   1024   // per-bucket row capacity (n_b ~ 683 +/- 24)
#define BM    128
#define BN    128
#define BK    64

typedef unsigned short u16;
typedef __attribute__((ext_vector_type(4))) unsigned short u16x4;
typedef __attribute__((ext_vector_type(8))) unsigned short u16x8;
typedef __attribute__((ext_vector_type(8))) __bf16 bf16x8;
typedef __attribute__((ext_vector_type(16))) float f32x16;

__device__ __forceinline__ u16 f2bf(float f) {
  unsigned int u = __float_as_uint(f);
  u += 0x7FFFu + ((u >> 16) & 1u);
  return (u16)(u >> 16);
}

// bucket tables: b: 0:(0,1) 1:(0,2) 2:(0,3) 3:(1,2) 4:(1,3) 5:(2,3)
// KB[b] = d_i + d_j + 64;  FSB[b] = prefix sum of CAP*KB (u16 elements)
#define FS_TOTAL 8257536   // 1024*(1856+1344+1088+1600+1344+832)

__global__ __launch_bounds__(64) void zero_kernel(int* cnt) {
  if (threadIdx.x < 6) cnt[threadIdx.x] = 0;
}

// ---------------------------------------------------------------------------
// prep (512 thr): blocks [0,256): grid-stride pack W -> bf16 WP [FDIM][KP]
//                 blocks [256,768): gate (8 rows/block) -> compacted FS rows
// (byte-identical to R5/R6 prep)
// ---------------------------------------------------------------------------
#define PACK_BLOCKS 256
#define GATE_BLOCKS 512    // BATCH / 8

__global__ __launch_bounds__(512) void prep_kernel(
    const float* __restrict__ f0, const float* __restrict__ f1,
    const float* __restrict__ f2, const float* __restrict__ f3,
    const float* __restrict__ gw, const float* __restrict__ gb,
    const float* __restrict__ w0, const float* __restrict__ w1,
    const float* __restrict__ w2, const float* __restrict__ w3,
    const float* __restrict__ b0, const float* __restrict__ b1,
    const float* __restrict__ b2, const float* __restrict__ b3,
    u16* __restrict__ wp, u16* __restrict__ fs,
    int* __restrict__ cnt, int* __restrict__ table)
{
  if (blockIdx.x < PACK_BLOCKS) {
    // grid-stride over 16 B chunks; KP/8 = 328 chunks per row
    const int total = FDIM * (KP / 8);   // 671744
    for (int chunk = blockIdx.x * 512 + threadIdx.x; chunk < total;
         chunk += PACK_BLOCKS * 512) {
      int j = chunk / 328;
      int s = chunk - j * 328;
      u16x8 o;
      if (s < 320) {
        const float* src; int col;
        if (s < 96)       { src = w0 + j * 768;  col = s * 8; }
        else if (s < 224) { src = w1 + j * 1024; col = (s - 96) * 8; }
        else if (s < 288) { src = w2 + j * 512;  col = (s - 224) * 8; }
        else              { src = w3 + j * 256;  col = (s - 288) * 8; }
        float4 v0 = *(const float4*)(src + col);
        float4 v1 = *(const float4*)(src + col + 4);
        o[0] = f2bf(v0.x); o[1] = f2bf(v0.y); o[2] = f2bf(v0.z); o[3] = f2bf(v0.w);
        o[4] = f2bf(v1.x); o[5] = f2bf(v1.y); o[6] = f2bf(v1.z); o[7] = f2bf(v1.w);
      } else if (s == 320) {
        o[0] = f2bf(b0[j]); o[1] = f2bf(b1[j]); o[2] = f2bf(b2[j]); o[3] = f2bf(b3[j]);
        o[4] = 0; o[5] = 0; o[6] = 0; o[7] = 0;
      } else {
        o = (u16x8)(u16)0;
      }
      *(u16x8*)(wp + (size_t)j * KP + s * 8) = o;
    }
    return;
  }

  // ---- gate: one WAVE per row, 8 rows per block
  const int wave = threadIdx.x >> 6;
  const int lane = threadIdx.x & 63;
  const int b    = (blockIdx.x - PACK_BLOCKS) * 8 + wave;

  float4 fv[10];
  float a[4] = {0.f, 0.f, 0.f, 0.f};
#pragma unroll
  for (int i = 0; i < 10; ++i) {
    int c4 = lane + i * 64;
    const float4* fp;
    if (c4 < 192)      fp = (const float4*)f0 + b * 192 + c4;
    else if (c4 < 448) fp = (const float4*)f1 + b * 256 + (c4 - 192);
    else if (c4 < 576) fp = (const float4*)f2 + b * 128 + (c4 - 448);
    else               fp = (const float4*)f3 + b * 64  + (c4 - 576);
    float4 v = *fp;
    fv[i] = v;
#pragma unroll
    for (int e = 0; e < 4; ++e) {
      float4 g = *((const float4*)(gw + e * DIN) + c4);
      a[e] += v.x * g.x + v.y * g.y + v.z * g.z + v.w * g.w;
    }
  }
#pragma unroll
  for (int e = 0; e < 4; ++e) {
#pragma unroll
    for (int m = 32; m >= 1; m >>= 1) a[e] += __shfl_xor(a[e], m, 64);
    a[e] += gb[e];
  }

  float mx = fmaxf(fmaxf(a[0], a[1]), fmaxf(a[2], a[3]));
  float ex[4], ssum = 0.f;
#pragma unroll
  for (int e = 0; e < 4; ++e) { ex[e] = __expf(a[e] - mx); ssum += ex[e]; }
  int i1 = 0;
#pragma unroll
  for (int e = 1; e < 4; ++e) if (a[e] > a[i1]) i1 = e;
  int i2 = -1;
#pragma unroll
  for (int e = 0; e < 4; ++e) {
    if (e == i1) continue;
    if (i2 < 0 || a[e] > a[i2]) i2 = e;
  }
  float inv = 1.f / ssum;
  float g[4];
#pragma unroll
  for (int e = 0; e < 4; ++e) g[e] = (e == i1 || e == i2) ? ex[e] * inv : 0.f;

  const int lo = min(i1, i2), hi = max(i1, i2);
  const int bucket = (lo == 0) ? (hi - 1) : (lo == 1) ? (hi + 1) : 5;

  // block-aggregated slot assignment: <=6 atomics per block, amortized 8 rows
  __shared__ int bkt[8];
  __shared__ int base6[6];
  if (lane == 0) bkt[wave] = bucket;
  __syncthreads();
  if (threadIdx.x < 6) {
    int c = 0;
#pragma unroll
    for (int w = 0; w < 8; ++w) c += (bkt[w] == (int)threadIdx.x);
    base6[threadIdx.x] = c ? atomicAdd(&cnt[threadIdx.x], c) : 0;
  }
  __syncthreads();
  int rank = 0;
  for (int w = 0; w < wave; ++w) rank += (bkt[w] == bucket);
  const int slot = base6[bucket] + rank;
  if (lane == 0) table[bucket * CAP + slot] = b;

  const int KB6[6]  = {1856, 1344, 1088, 1600, 1344, 832};
  const int FSB6[6] = {0, 1900544, 3276800, 4390912, 6029312, 7405568};
  const int DL[4]   = {768, 1024, 512, 256};
  const int S0[4]   = {0, 192, 448, 576};       // src starts (float4 units)
  const int EX[10]  = {0, 0, 0, 1, 1, 1, 1, 2, 2, 3};

  const int dlo4 = DL[lo] >> 2;
  u16* row = fs + FSB6[bucket] + (size_t)slot * KB6[bucket];
#pragma unroll
  for (int i = 0; i < 10; ++i) {
    const int e  = EX[i];
    const int c4 = lane + i * 64;
    if (e == lo || e == hi) {
      int dst = (c4 - S0[e]) + ((e == hi) ? dlo4 : 0);
      float gg = g[e];
      u16x4 o = { f2bf(fv[i].x * gg), f2bf(fv[i].y * gg),
                  f2bf(fv[i].z * gg), f2bf(fv[i].w * gg) };
      *(u16x4*)(row + dst * 4) = o;
    }
  }
  // bias block: 64 cols at d_lo+d_hi; col e = g_e (zeros elsewhere, must clear)
  if (lane < 16) {
    int base = DL[lo] + DL[hi];
    u16x4 o = { (u16)0, (u16)0, (u16)0, (u16)0 };
    if (lane == 0) { o[0] = f2bf(g[0]); o[1] = f2bf(g[1]);
                     o[2] = f2bf(g[2]); o[3] = f2bf(g[3]); }
    *(u16x4*)(row + base + lane * 4) = o;
  }
}

// ---------------------------------------------------------------------------
// gemm v3: per-bucket C[rows(b)][2048] = FS_b @ [w_i|w_j|bias]^T
// 128x128 tile, BK=64, 256 thr = 4 waves (2x2 of 64x64 wave tiles),
// mfma_32x32x16 (acc 2x2x16). DOUBLE-BUFFERED LDS (2 x 32 KB), one barrier
// per K-step: barrier -> issue loads(k+1) into buf p^1 -> compute buf p.
// The vmcnt(0) drain at the next barrier overlaps a full compute phase.
// 8-way XOR swizzle on 16 B chunks (0 conflicts measured with this scheme).
// ---------------------------------------------------------------------------
__device__ __forceinline__ void gld16(const u16* g, u16* l) {
  __builtin_amdgcn_global_load_lds(
      (const __attribute__((address_space(1))) unsigned int*)(uintptr_t)g,
      (__attribute__((address_space(3))) unsigned int*)(unsigned int)(uintptr_t)l,
      16, 0, 0);
}

__global__ __launch_bounds__(256, 2) void gemm_kernel(
    const u16* __restrict__ fs, const u16* __restrict__ wp,
    const int* __restrict__ cnt, const int* __restrict__ table,
    float* __restrict__ C)
{
  const int KB6[6]  = {1856, 1344, 1088, 1600, 1344, 832};
  const int FSB6[6] = {0, 1900544, 3276800, 4390912, 6029312, 7405568};
  const int LOE[6]  = {0, 0, 0, 1, 1, 2};
  const int HIE[6]  = {1, 2, 3, 2, 3, 3};
  const int WOFF[4] = {0, 768, 1792, 2304};
  const int DL[4]   = {768, 1024, 512, 256};

  const int bucket = blockIdx.x >> 7;       // 8 mtiles x 16 ntiles per bucket
  const int rr     = blockIdx.x & 127;
  const int mtile  = rr >> 4;
  const int ntile  = rr & 15;
  const int nb     = cnt[bucket];
  if (mtile * BM >= nb) return;

  const int kb = KB6[bucket];
  const int di = DL[LOE[bucket]], dj = DL[HIE[bucket]];
  const int wi = WOFF[LOE[bucket]], wj = WOFF[HIE[bucket]];

  __shared__ u16 As[2][BM * BK];   // 2 x 16 KB
  __shared__ u16 Bs[2][BN * BK];   // 2 x 16 KB

  const int tid  = threadIdx.x;
  const int wave = tid >> 6;
  const int lane = tid & 63;
  const int wm   = (wave >> 1) * 64;   // 2x2 wave grid, wave tile 64x64
  const int wn   = (wave & 1) * 64;
  const int l31  = lane & 31;
  const int lh   = lane >> 5;          // half-wave: k-offset selector

  // staging geometry: tile = 1024 chunks of 16 B; 4 chunks per thread.
  // LDS[row][slot] <- G[row][slot ^ (row&7)]  (8-way XOR swizzle)
  int srow[4], scol[4];
#pragma unroll
  for (int i = 0; i < 4; ++i) {
    int c = tid + i * 256;
    srow[i] = c >> 3;
    scol[i] = ((c & 7) ^ (srow[i] & 7)) * 8;
  }

  const u16* Ab = fs + FSB6[bucket] + (size_t)(mtile * BM) * kb;
  const u16* Bb = wp + (size_t)(ntile * BN) * KP;

  f32x16 acc[2][2] = {};

  // prologue: stage k0=0 into buffer 0
  {
    const int bcol = wi;   // k0=0 always in lo-expert segment
#pragma unroll
    for (int i = 0; i < 4; ++i) {
      gld16(Ab + (size_t)srow[i] * kb + scol[i], &As[0][(tid + i * 256) * 8]);
      gld16(Bb + (size_t)srow[i] * KP + bcol + scol[i], &Bs[0][(tid + i * 256) * 8]);
    }
  }

  int p = 0;
  for (int k0 = 0; k0 < kb; k0 += BK) {
    __syncthreads();   // drains loads for buf p (issued last iter / prologue)

    const int kn = k0 + BK;
    if (kn < kb) {     // issue next tile's loads FIRST, then compute
      const int bcol = (kn < di) ? wi + kn
                     : (kn < di + dj) ? wj + (kn - di)
                     : 2560 + (kn - di - dj);
      const int q = p ^ 1;
#pragma unroll
      for (int i = 0; i < 4; ++i) {
        gld16(Ab + (size_t)srow[i] * kb + kn + scol[i],
              &As[q][(tid + i * 256) * 8]);
        gld16(Bb + (size_t)srow[i] * KP + bcol + scol[i],
              &Bs[q][(tid + i * 256) * 8]);
      }
    }

    // compute buf p: 4 k-chunks of 16, 2x2 MFMAs each
    const u16* Asp = As[p];
    const u16* Bsp = Bs[p];
#pragma unroll
    for (int kk = 0; kk < 4; ++kk) {
      const int ch = kk * 2 + lh;        // 16 B chunk index for this K=16 slab
      bf16x8 af[2], bf[2];
#pragma unroll
      for (int m = 0; m < 2; ++m) {
        const int row = wm + m * 32 + l31;
        af[m] = __builtin_bit_cast(bf16x8,
                  *(const u16x8*)&Asp[row * BK + (ch ^ (row & 7)) * 8]);
      }
#pragma unroll
      for (int n = 0; n < 2; ++n) {
        const int row = wn + n * 32 + l31;
        bf[n] = __builtin_bit_cast(bf16x8,
                  *(const u16x8*)&Bsp[row * BK + (ch ^ (row & 7)) * 8]);
      }
#pragma unroll
      for (int m = 0; m < 2; ++m)
#pragma unroll
        for (int n = 0; n < 2; ++n)
          acc[m][n] = __builtin_amdgcn_mfma_f32_32x32x16_bf16(af[m], bf[n],
                                                              acc[m][n], 0, 0, 0);
    }
    p ^= 1;
  }

  // epilogue: 32x32 C/D layout: col=lane&31, row=(reg&3)+8*(reg>>2)+4*lh
#pragma unroll
  for (int m = 0; m < 2; ++m) {
#pragma unroll
    for (int reg = 0; reg < 16; ++reg) {
      const int rin  = (reg & 3) + 8 * (reg >> 2) + 4 * lh;
      const int slot = mtile * BM + wm + m * 32 + rin;
      if (slot < nb) {
        const int rowg = table[bucket * CAP + slot];
#pragma unroll
        for (int n = 0; n < 2; ++n) {
          const int col = ntile * BN + wn + n * 32 + l31;
          C[(size_t)rowg * FDIM + col] = acc[m][n][reg];
        }
      }
    }
  }
}

// ---------------------------------------------------------------------------
extern "C" void kernel_launch(void* const* d_in, const int* in_sizes, int n_in,
                              void* d_out, int out_size, void* d_ws, size_t ws_size,
                              hipStream_t stream) {
  (void)in_sizes; (void)n_in; (void)out_size; (void)ws_size;
  const float* f0 = (const float*)d_in[0];
  const float* f1 = (const float*)d_in[1];
  const float* f2 = (const float*)d_in[2];
  const float* f3 = (const float*)d_in[3];
  const float* gw = (const float*)d_in[4];
  const float* gb = (const float*)d_in[5];
  const float* w0 = (const float*)d_in[6];
  const float* b0 = (const float*)d_in[7];
  const float* w1 = (const float*)d_in[8];
  const float* b1 = (const float*)d_in[9];
  const float* w2 = (const float*)d_in[10];
  const float* b2 = (const float*)d_in[11];
  const float* w3 = (const float*)d_in[12];
  const float* b3 = (const float*)d_in[13];
  float* out = (float*)d_out;

  char* ws = (char*)d_ws;
  u16* wp    = (u16*)ws;                                   // 2048*2624*2 B
  u16* fs    = (u16*)(ws + (size_t)FDIM * KP * 2);         // FS_TOTAL*2 B
  int* cnt   = (int*)(ws + (size_t)FDIM * KP * 2 + (size_t)FS_TOTAL * 2);
  int* table = cnt + 16;                                   // 6*CAP ints

  hipLaunchKernelGGL(zero_kernel, dim3(1), dim3(64), 0, stream, cnt);
  hipLaunchKernelGGL(prep_kernel, dim3(PACK_BLOCKS + GATE_BLOCKS), dim3(512), 0,
                     stream, f0, f1, f2, f3, gw, gb,
                     w0, w1, w2, w3, b0, b1, b2, b3, wp, fs, cnt, table);
  hipLaunchKernelGGL(gemm_kernel, dim3(6 * 8 * 16), dim3(256), 0, stream,
                     fs, wp, cnt, table, out);
}